// Round 13
// baseline (112.424 us; speedup 1.0000x reference)
//
#include <hip/hip_runtime.h>
#include <cstddef>

#define EPS 1e-6f
constexpr float INV_SQRT_E = 0.6065306597126334f;  // exp(-0.5*THETA^2), THETA=1

// R12 (77.6 us) + wider row-group sharing + paired staging writes.
//  - Vertical & SAD walks share taps across row groups of stride D inside the
//    8-row tile: D=2 QUADS (0,2,4,6)/(1,3,5,7); D=3 TRIPLES (0,3,6)/(1,4,7) +
//    pair (2,5)  [kills R12's 98-read critical wave]; D=4 pairs (structural).
//  - Staging writes 2 adjacent elements per thread: ds_write_b64 per plane
//    instead of 2x b32 (halves staging write instructions).
// Config (unchanged, best measured): block (64,8), TH=8, LDS 39,936 B ->
// 4 blocks/CU = 32 waves/CU; 4096 blocks; dilation in fast z bits; NT stores.

// Walker: rows b, b+D, ..., b+(n-1)D; taps t in [0, KS+n-1), row b+tD;
// tap t contributes to pixel j iff j <= t < j+KS.
template <int D, int KS, int LW, int n>
__device__ __forceinline__ void vwalk(int b, int c, const float* sx,
                                      const float* slg, float2* cs2, float* cs1)
{
    float s[n], q[n], l[n];
    #pragma unroll
    for (int j = 0; j < n; ++j) { s[j] = 0.f; q[j] = 0.f; l[j] = 0.f; }
    const float* cx = sx  + b * LW + c;
    const float* cl = slg + b * LW + c;
    #pragma unroll
    for (int t = 0; t < KS + n - 1; ++t) {
        const float v = cx[t * D * LW];
        const float g = cl[t * D * LW];
        #pragma unroll
        for (int j = 0; j < n; ++j)
            if (j <= t && t < j + KS) { s[j] += v; q[j] = fmaf(v, v, q[j]); l[j] += g; }
    }
    #pragma unroll
    for (int j = 0; j < n; ++j) {
        const int r = b + j * D;
        cs2[r * LW + c] = make_float2(s[j], q[j]);
        cs1[r * LW + c] = l[j];
    }
}

template <int D, int KS, int LW, int n>
__device__ __forceinline__ void swalk(int b, int tx, const float* sx,
                                      const float* muP, float* sadP)
{
    float mu[n], sad[n];
    #pragma unroll
    for (int j = 0; j < n; ++j) { mu[j] = muP[(b + j * D) * 64 + tx]; sad[j] = 0.f; }
    const float* bp = sx + b * LW + tx;
    #pragma unroll
    for (int mj = 0; mj < KS; ++mj) {
        const float* cp = bp + mj * D;
        #pragma unroll
        for (int t = 0; t < KS + n - 1; ++t) {
            const float v = cp[t * D * LW];
            #pragma unroll
            for (int j = 0; j < n; ++j)
                if (j <= t && t < j + KS) sad[j] += fabsf(v - mu[j]);
        }
    }
    #pragma unroll
    for (int j = 0; j < n; ++j) sadP[(b + j * D) * 64 + tx] = sad[j];
}

template <int D>
__device__ __forceinline__ void body(const float* __restrict__ x,
                                     float* __restrict__ out,
                                     char* smem, int bc, int H, int W)
{
    constexpr int PAD = D * D;          // halo per side
    constexpr int KS  = 2 * D + 1;      // taps per axis
    constexpr int K   = KS * KS;        // patch size
    constexpr int TW  = 64, TH = 8;
    constexpr int LW  = TW + 2 * PAD;
    constexpr int LH  = TH + 2 * PAD;
    constexpr int NE  = LH * LW;        // even for all D
    constexpr int NP  = NE / 2;
    constexpr int NI2 = (NP + 511) / 512;
    constexpr float INVK = 1.0f / (float)K;
    constexpr float UNB  = (float)K / (float)(K - 1);

    float*  sx  = (float*)smem;                 // [NE] v
    float*  slg = sx + NE;                      // [NE] v*log(v+eps)
    float2* cs2 = (float2*)(slg + NE);          // [TH*LW] {col_s, col_s2}
    float*  cs1 = (float*)(cs2 + TH * LW);      // [TH*LW] col_sl
    // Exchange planes aliased into cs2 (dead after horizontal; >=4608 B).
    float*  muP  = (float*)cs2;                 // [TH*64]
    float*  sadP = muP + TH * 64;               // [TH*64]

    const int w0 = blockIdx.x * TW;
    const int h0 = blockIdx.y * TH;
    const float* xp = x + (size_t)bc * H * W;
    const int tid = threadIdx.y * 64 + threadIdx.x;

    // ---- Staging: batched global loads of element PAIRS, b64 plane writes.
    float va[NI2], vb[NI2];
    #pragma unroll
    for (int i = 0; i < NI2; ++i) {
        const int e = tid + i * 512;
        float v0 = 0.f, v1 = 0.f;
        if (e < NP) {
            const int i0 = 2 * e;                 // LW even: pair in one row
            const int r  = i0 / LW;
            const int c  = i0 - r * LW;
            const int gh = h0 - PAD + r;
            const int gw = w0 - PAD + c;
            if (gh >= 0 && gh < H) {
                const float* rp = xp + (size_t)gh * W;
                if ((unsigned)gw < (unsigned)W)       v0 = rp[gw];
                if ((unsigned)(gw + 1) < (unsigned)W) v1 = rp[gw + 1];
            }
        }
        va[i] = v0; vb[i] = v1;
    }
    #pragma unroll
    for (int i = 0; i < NI2; ++i) {
        const int e = tid + i * 512;
        if (e < NP) {
            const int i0 = 2 * e;
            *(float2*)(sx + i0)  = make_float2(va[i], vb[i]);
            *(float2*)(slg + i0) = make_float2(va[i] * __logf(va[i] + EPS),
                                               vb[i] * __logf(vb[i] + EPS));
        }
    }
    __syncthreads();

    const int tx = threadIdx.x;
    const int ty = threadIdx.y;

    if constexpr (K <= 9) {
        // ---- D=1: single pass, taps cached in registers. ----
        const float* bx = sx  + ty * LW + tx;
        const float* bl = slg + ty * LW + tx;
        float s = 0.f, s2 = 0.f, sl = 0.f, ta[K];
        #pragma unroll
        for (int mi = 0; mi < KS; ++mi)
            #pragma unroll
            for (int mj = 0; mj < KS; ++mj) {
                const float v = bx[mi * LW + mj];
                ta[mi * KS + mj] = v;
                s  += v;
                s2  = fmaf(v, v, s2);
                sl += bl[mi * LW + mj];
            }
        const float mu = s * INVK;
        float sad = 0.f;
        #pragma unroll
        for (int i = 0; i < K; ++i) sad += fabsf(ta[i] - mu);

        const float energy   = s2 * INVK;
        const float var      = fmaxf(energy - mu * mu, 0.f);
        const float sd       = sqrtf(var * UNB) + EPS;
        const float contrast = var / (sd * sd);
        const float entropy  = -sl * INVK;
        const float homog    = 1.f / (1.f + sad * INVK);
        const size_t fs = (size_t)H * W;
        const size_t ro = (size_t)(h0 + ty) * W;
        float* op = out + (size_t)bc * 4 * fs + w0 + tx;
        __builtin_nontemporal_store((contrast + EPS) * INV_SQRT_E, &op[0 * fs + ro]);
        __builtin_nontemporal_store((energy   + EPS) * INV_SQRT_E, &op[1 * fs + ro]);
        __builtin_nontemporal_store((entropy  + EPS) * INV_SQRT_E, &op[2 * fs + ro]);
        __builtin_nontemporal_store((homog    + EPS) * INV_SQRT_E, &op[3 * fs + ro]);
        return;
    } else {
        // ---- Vertical stage: grouped column-sum walks. ----
        const int e = tid;
        if constexpr (D == 2) {
            if (e < 2 * LW) {               // quads (0,2,4,6),(1,3,5,7)
                const int w = e / LW, c = e - w * LW;
                vwalk<D, KS, LW, 4>(w, c, sx, slg, cs2, cs1);
            }
        } else if constexpr (D == 3) {
            if (e < 3 * LW) {               // triples (0,3,6),(1,4,7) + pair (2,5)
                const int w = e / LW, c = e - w * LW;
                if (w < 2) vwalk<D, KS, LW, 3>(w, c, sx, slg, cs2, cs1);
                else       vwalk<D, KS, LW, 2>(2, c, sx, slg, cs2, cs1);
            }
        } else {                            // D==4: pairs (0,4)..(3,7)
            if (e < 4 * LW) {
                const int w = e / LW, c = e - w * LW;
                vwalk<D, KS, LW, 2>(w, c, sx, slg, cs2, cs1);
            }
        }
        __syncthreads();

        // ---- Horizontal stage: KS taps over column sums. ----
        float s = 0.f, s2 = 0.f, sl = 0.f;
        const float2* q2 = cs2 + ty * LW + tx;
        const float*  q1 = cs1 + ty * LW + tx;
        #pragma unroll
        for (int mj = 0; mj < KS; ++mj) {
            const float2 q = q2[mj * D];
            s += q.x; s2 += q.y; sl += q1[mj * D];
        }
        const float mu = s * INVK;
        __syncthreads();                 // cs reads done; muP aliases cs2

        muP[ty * 64 + tx] = mu;
        __syncthreads();

        // ---- SAD: grouped walks by owner waves (ty = wave id, uniform). ----
        if constexpr (D == 2) {
            if (ty < 2) swalk<D, KS, LW, 4>(ty, tx, sx, muP, sadP);
        } else if constexpr (D == 3) {
            if (ty < 2)       swalk<D, KS, LW, 3>(ty, tx, sx, muP, sadP);
            else if (ty == 2) swalk<D, KS, LW, 2>(2,  tx, sx, muP, sadP);
        } else {
            if (ty < 4) swalk<D, KS, LW, 2>(ty, tx, sx, muP, sadP);
        }
        __syncthreads();
        const float sad = sadP[ty * 64 + tx];

        // ---- Epilogue. ----
        const float energy   = s2 * INVK;
        const float var      = fmaxf(energy - mu * mu, 0.f);
        const float sd       = sqrtf(var * UNB) + EPS;
        const float contrast = var / (sd * sd);
        const float entropy  = -sl * INVK;
        const float homog    = 1.f / (1.f + sad * INVK);
        const size_t fs = (size_t)H * W;
        const size_t ro = (size_t)(h0 + ty) * W;
        float* op = out + (size_t)bc * 4 * fs + w0 + tx;
        __builtin_nontemporal_store((contrast + EPS) * INV_SQRT_E, &op[0 * fs + ro]);
        __builtin_nontemporal_store((energy   + EPS) * INV_SQRT_E, &op[1 * fs + ro]);
        __builtin_nontemporal_store((entropy  + EPS) * INV_SQRT_E, &op[2 * fs + ro]);
        __builtin_nontemporal_store((homog    + EPS) * INV_SQRT_E, &op[3 * fs + ro]);
    }
}

__global__ __launch_bounds__(512, 8) void tex_fused(
    const float* __restrict__ x, float* __restrict__ out, int H, int W)
{
    extern __shared__ __align__(16) char smem[];
    const int dz = blockIdx.z & 3;       // dilation in fast bits: co-resident
    const int bc = blockIdx.z >> 2;      // blocks on a CU mix D1..D4
    const size_t per = (size_t)8 * 4 * H * W;
    switch (dz) {
        case 0: body<4>(x, out + 3 * per, smem, bc, H, W); break;
        case 1: body<3>(x, out + 2 * per, smem, bc, H, W); break;
        case 2: body<2>(x, out + 1 * per, smem, bc, H, W); break;
        default: body<1>(x, out + 0 * per, smem, bc, H, W); break;
    }
}

extern "C" void kernel_launch(void* const* d_in, const int* in_sizes, int n_in,
                              void* d_out, int out_size, void* d_ws, size_t ws_size,
                              hipStream_t stream) {
    const float* x = (const float*)d_in[0];
    float* out = (float*)d_out;

    const int H = 256, W = 256;
    // Per-D LDS (TH=8, PAD=D*D): 2 b32 planes LH*LW*8 + cs2 TH*LW*8 + cs1 TH*LW*4
    //   D=4: LH=40, LW=96: 30720 + 6144 + 3072 = 39936  (max) -> 4 blocks/CU
    //   D=3: LH=26, LW=82: 17056 + 5248 + 2624 = 24928
    //   D=2: LH=16, LW=72:  9216 + 4608 + 2304 = 16128
    //   D=1: LH=10, LW=66:  5280 (register path; cs unused)
    const size_t smem_bytes = 39936;

    dim3 blk(64, 8, 1);
    dim3 grd(W / 64, H / 8, 8 * 4);      // 4 x-tiles, 32 y-tiles, (bc x dz)
    tex_fused<<<grd, blk, smem_bytes, stream>>>(x, out, H, W);
}

// Round 14
// 77.335 us; speedup vs baseline: 1.4537x; 1.4537x over previous
//
#include <hip/hip_runtime.h>
#include <cstddef>

#define EPS 1e-6f
constexpr float INV_SQRT_E = 0.6065306597126334f;  // exp(-0.5*THETA^2), THETA=1

// R12 VERBATIM — verified best (77.6 us; dispatch ~22 us, no spills).
// R13's wider (n=3/n=4) walkers spilled at the 64-VGPR tier (VGPR=32 quantum,
// ~85 MB scratch traffic) — pair-walks are the spill-safe sharing width.
//  1. SPLIT sx / slg planes (b32, stride-1, conflict-free).
//  2. SAD PAIR-WALK: rows (r, r+D) share KS-1 of KS tap rows; owner threads
//     (ty<4) walk KS+1 rows per column tap for 2 pixels.
//  3. Vertical stage pair-walk (same sharing on column sums).
// Config: block (64,8), TH=8, LDS 39,936 B -> 4 blocks/CU = 32 waves/CU.
template <int D>
__device__ __forceinline__ void body(const float* __restrict__ x,
                                     float* __restrict__ out,
                                     char* smem, int bc, int H, int W)
{
    constexpr int PAD = D * D;          // halo per side
    constexpr int KS  = 2 * D + 1;      // taps per axis
    constexpr int K   = KS * KS;        // patch size
    constexpr int TW  = 64, TH = 8;
    constexpr int LW  = TW + 2 * PAD;
    constexpr int LH  = TH + 2 * PAD;
    constexpr int NE  = LH * LW;
    constexpr int NI  = (NE + 511) / 512;
    constexpr float INVK = 1.0f / (float)K;
    constexpr float UNB  = (float)K / (float)(K - 1);

    float*  sx  = (float*)smem;                 // [NE] v
    float*  slg = sx + NE;                      // [NE] v*log(v+eps)
    float2* cs2 = (float2*)(slg + NE);          // [TH*LW] {col_s, col_s2}
    float*  cs1 = (float*)(cs2 + TH * LW);      // [TH*LW] col_sl
    // Aliased exchange planes (cs2 region is dead after the horizontal stage;
    // needs 4096 B, cs2 has >= 4608 B for D>=2).
    float*  muP  = (float*)cs2;                 // [TH*64]
    float*  sadP = muP + TH * 64;               // [TH*64]

    const int w0 = blockIdx.x * TW;
    const int h0 = blockIdx.y * TH;
    const float* xp = x + (size_t)bc * H * W;
    const int tid = threadIdx.y * 64 + threadIdx.x;

    // ---- Staging: batched global loads, then split-plane LDS writes. ----
    float vb[NI];
    #pragma unroll
    for (int i = 0; i < NI; ++i) {
        const int idx = tid + i * 512;
        float v = 0.0f;
        if (idx < NE) {
            const int r  = idx / LW;
            const int cc = idx - r * LW;
            const int gh = h0 - PAD + r;
            const int gw = w0 - PAD + cc;
            if (gh >= 0 && gh < H && gw >= 0 && gw < W) v = xp[gh * W + gw];
        }
        vb[i] = v;
    }
    #pragma unroll
    for (int i = 0; i < NI; ++i) {
        const int idx = tid + i * 512;
        if (idx < NE) {
            sx[idx]  = vb[i];
            slg[idx] = vb[i] * __logf(vb[i] + EPS);   // v=0 -> exactly 0
        }
    }
    __syncthreads();

    const int tx = threadIdx.x;
    const int ty = threadIdx.y;

    if constexpr (K <= 9) {
        // ---- D=1: single pass, taps cached in registers. ----
        const float* bx = sx  + ty * LW + tx;
        const float* bl = slg + ty * LW + tx;
        float s = 0.f, s2 = 0.f, sl = 0.f, ta[K];
        #pragma unroll
        for (int mi = 0; mi < KS; ++mi)
            #pragma unroll
            for (int mj = 0; mj < KS; ++mj) {
                const float v = bx[mi * LW + mj];
                ta[mi * KS + mj] = v;
                s  += v;
                s2  = fmaf(v, v, s2);
                sl += bl[mi * LW + mj];
            }
        const float mu = s * INVK;
        float sad = 0.f;
        #pragma unroll
        for (int i = 0; i < K; ++i) sad += fabsf(ta[i] - mu);

        const float energy   = s2 * INVK;
        const float var      = fmaxf(energy - mu * mu, 0.f);
        const float sd       = sqrtf(var * UNB) + EPS;
        const float contrast = var / (sd * sd);
        const float entropy  = -sl * INVK;
        const float homog    = 1.f / (1.f + sad * INVK);
        const size_t fs = (size_t)H * W;
        const size_t ro = (size_t)(h0 + ty) * W;
        float* op = out + (size_t)bc * 4 * fs + w0 + tx;
        __builtin_nontemporal_store((contrast + EPS) * INV_SQRT_E, &op[0 * fs + ro]);
        __builtin_nontemporal_store((energy   + EPS) * INV_SQRT_E, &op[1 * fs + ro]);
        __builtin_nontemporal_store((entropy  + EPS) * INV_SQRT_E, &op[2 * fs + ro]);
        __builtin_nontemporal_store((homog    + EPS) * INV_SQRT_E, &op[3 * fs + ro]);
        return;
    } else {
        // ---- Vertical stage: PAIR-WALK column sums. Pairs over rows 0..7:
        //  D=2: (0,2)(1,3)(4,6)(5,7)  D=3: (0,3)(1,4)(2,5)+{6,7} indep
        //  D=4: (0,4)(1,5)(2,6)(3,7)
        for (int e = tid; e < 4 * LW; e += 512) {
            const int p = e / LW;
            const int c = e - p * LW;
            const int vA = (D == 2) ? ((p < 2) ? p : p + 2) : p;
            if (!(D == 3 && p == 3)) {
                const int vB = vA + D;
                const float* cx = sx  + vA * LW + c;
                const float* cl = slg + vA * LW + c;
                float sA = 0, qA = 0, lA = 0, sB = 0, qB = 0, lB = 0;
                #pragma unroll
                for (int t = 0; t <= KS; ++t) {
                    const float v = cx[t * D * LW];
                    const float g = cl[t * D * LW];
                    if (t < KS)  { sA += v; qA = fmaf(v, v, qA); lA += g; }
                    if (t >= 1)  { sB += v; qB = fmaf(v, v, qB); lB += g; }
                }
                cs2[vA * LW + c] = make_float2(sA, qA); cs1[vA * LW + c] = lA;
                cs2[vB * LW + c] = make_float2(sB, qB); cs1[vB * LW + c] = lB;
            } else {            // D=3 leftover rows 6,7: independent walks
                #pragma unroll
                for (int rr = 6; rr <= 7; ++rr) {
                    const float* cx = sx  + rr * LW + c;
                    const float* cl = slg + rr * LW + c;
                    float s = 0, q = 0, l = 0;
                    #pragma unroll
                    for (int mi = 0; mi < KS; ++mi) {
                        const float v = cx[mi * D * LW];
                        s += v; q = fmaf(v, v, q); l += cl[mi * D * LW];
                    }
                    cs2[rr * LW + c] = make_float2(s, q); cs1[rr * LW + c] = l;
                }
            }
        }
        __syncthreads();

        // ---- Horizontal stage: KS taps over column sums. ----
        float s = 0.f, s2 = 0.f, sl = 0.f;
        const float2* q2 = cs2 + ty * LW + tx;
        const float*  q1 = cs1 + ty * LW + tx;
        #pragma unroll
        for (int mj = 0; mj < KS; ++mj) {
            const float2 q = q2[mj * D];
            s += q.x; s2 += q.y; sl += q1[mj * D];
        }
        const float mu = s * INVK;
        __syncthreads();                 // cs reads done; muP may alias cs2

        muP[ty * 64 + tx] = mu;
        __syncthreads();

        // ---- SAD: pair-walk by owner threads (waves 0..3). ----
        if (ty < 4) {
            const int o = ty;
            if (!(D == 3 && o == 3)) {
                const int rA = (D == 2) ? ((o < 2) ? o : o + 2) : o;
                const int rB = rA + D;
                const float muA = muP[rA * 64 + tx];
                const float muB = muP[rB * 64 + tx];
                float sadA = 0.f, sadB = 0.f;
                const float* bp = sx + rA * LW + tx;
                #pragma unroll
                for (int mj = 0; mj < KS; ++mj) {
                    const float* cp = bp + mj * D;
                    #pragma unroll
                    for (int t = 0; t <= KS; ++t) {
                        const float v = cp[t * D * LW];
                        if (t < KS) sadA += fabsf(v - muA);
                        if (t >= 1) sadB += fabsf(v - muB);
                    }
                }
                sadP[rA * 64 + tx] = sadA;
                sadP[rB * 64 + tx] = sadB;
            } else {             // D=3 leftover rows 6,7: full K walks
                #pragma unroll
                for (int rr = 6; rr <= 7; ++rr) {
                    const float mur = muP[rr * 64 + tx];
                    const float* bp = sx + rr * LW + tx;
                    float sd = 0.f;
                    #pragma unroll
                    for (int mi = 0; mi < KS; ++mi)
                        #pragma unroll
                        for (int mj = 0; mj < KS; ++mj)
                            sd += fabsf(bp[mi * D * LW + mj * D] - mur);
                    sadP[rr * 64 + tx] = sd;
                }
            }
        }
        __syncthreads();
        const float sad = sadP[ty * 64 + tx];

        // ---- Epilogue. ----
        const float energy   = s2 * INVK;
        const float var      = fmaxf(energy - mu * mu, 0.f);
        const float sd       = sqrtf(var * UNB) + EPS;
        const float contrast = var / (sd * sd);
        const float entropy  = -sl * INVK;
        const float homog    = 1.f / (1.f + sad * INVK);
        const size_t fs = (size_t)H * W;
        const size_t ro = (size_t)(h0 + ty) * W;
        float* op = out + (size_t)bc * 4 * fs + w0 + tx;
        __builtin_nontemporal_store((contrast + EPS) * INV_SQRT_E, &op[0 * fs + ro]);
        __builtin_nontemporal_store((energy   + EPS) * INV_SQRT_E, &op[1 * fs + ro]);
        __builtin_nontemporal_store((entropy  + EPS) * INV_SQRT_E, &op[2 * fs + ro]);
        __builtin_nontemporal_store((homog    + EPS) * INV_SQRT_E, &op[3 * fs + ro]);
    }
}

__global__ __launch_bounds__(512, 8) void tex_fused(
    const float* __restrict__ x, float* __restrict__ out, int H, int W)
{
    extern __shared__ __align__(16) char smem[];
    const int dz = blockIdx.z & 3;       // dilation in fast bits: co-resident
    const int bc = blockIdx.z >> 2;      // blocks on a CU mix D1..D4
    const size_t per = (size_t)8 * 4 * H * W;
    switch (dz) {
        case 0: body<4>(x, out + 3 * per, smem, bc, H, W); break;
        case 1: body<3>(x, out + 2 * per, smem, bc, H, W); break;
        case 2: body<2>(x, out + 1 * per, smem, bc, H, W); break;
        default: body<1>(x, out + 0 * per, smem, bc, H, W); break;
    }
}

extern "C" void kernel_launch(void* const* d_in, const int* in_sizes, int n_in,
                              void* d_out, int out_size, void* d_ws, size_t ws_size,
                              hipStream_t stream) {
    const float* x = (const float*)d_in[0];
    float* out = (float*)d_out;

    const int H = 256, W = 256;
    // Per-D LDS (TH=8, PAD=D*D): 2 b32 planes LH*LW*8 + cs2 TH*LW*8 + cs1 TH*LW*4
    //   D=4: LH=40, LW=96: 30720 + 6144 + 3072 = 39936  (max) -> 4 blocks/CU
    //   D=3: LH=26, LW=82: 17056 + 5248 + 2624 = 24928
    //   D=2: LH=16, LW=72:  9216 + 4608 + 2304 = 16128
    //   D=1: LH=10, LW=66:  5280 (register path; cs unused)
    const size_t smem_bytes = 39936;

    dim3 blk(64, 8, 1);
    dim3 grd(W / 64, H / 8, 8 * 4);      // 4 x-tiles, 32 y-tiles, (bc x dz)
    tex_fused<<<grd, blk, smem_bytes, stream>>>(x, out, H, W);
}